// Round 8
// baseline (85.023 us; speedup 1.0000x reference)
//
#include <hip/hip_runtime.h>

// HashTable voxel-corner feature gather — quad-cooperative rows, persistent
// grid-stride, non-temporal output stores.
// coords: (4096,128,3) f32; table: (2^22, 16) f32; out: (4096,128,16) f32.
//
// CORRECTNESS-CRITICAL hash semantics (verified passing, rounds 5-6):
//  * voxel index: torch div-by-scalar = multiply-by-reciprocal:
//      bxi = floor(cx * 100.0f)   (NOT / 0.01f)
//  * base/voxel coords: strict f32 mul/add (NOFUSE barriers block FMA)
//  * hash einsum: FMA chain  h = fma(vz,P2, fma(vy,P1, round(vx*P0)))
//  * exact mod 2^22, trunc to int32.
//  DO NOT TOUCH the hash math.
//
// PERF structure:
//  * 4 lanes per point: lane (t&3) loads 16 B of the 64 B row -> lane-quad
//    requests coalesce into one 64 B transaction per row (round5->6: 4x
//    fetch reduction, 313->84 us).
//  * grid-stride persistent loop (2048 blocks): waves stay resident, next
//    iteration's gathers pipeline behind the previous store.
//  * non-temporal stores for out (via clang ext_vector type — HIP float4 is
//    a struct and rejected by the builtin): no write-allocate, L3 kept for
//    the table's ~3.2x corner reuse (~166 MB working set < 256 MB L3).

#define VS 0.01f

#define NOFUSE(x) asm volatile("" : "+v"(x))

typedef float f32x4 __attribute__((ext_vector_type(4)));

__global__ __launch_bounds__(256) void hash_gather_kernel(
    const float* __restrict__ coords,
    const float* __restrict__ table,
    float* __restrict__ out,
    int npts)
{
#pragma clang fp contract(off)
    const float P0 = 73856093.0f, P1 = 19349663.0f, P2 = 83492791.0f;
    const float ox[8] = {0.f, VS, VS, 0.f, 0.f, VS, VS, 0.f};
    const float oy[8] = {0.f, 0.f, VS, VS, 0.f, 0.f, VS, VS};
    const float oz[8] = {0.f, 0.f, 0.f, 0.f, VS, VS, VS, VS};
    const float inv_diag = 1.0f / (sqrtf(3.0f) * VS);

    const long long nthreads = (long long)npts * 4;
    const int stride = gridDim.x * blockDim.x;

    for (long long t = blockIdx.x * blockDim.x + threadIdx.x;
         t < nthreads; t += stride) {
        int p   = (int)(t >> 2);   // point index (4 lanes per point)
        int col = (int)(t & 3);    // float4 column of the 16-float row

        float cx = coords[3 * p + 0];
        float cy = coords[3 * p + 1];
        float cz = coords[3 * p + 2];

        // torch reciprocal-mul division, then floor (coords >= 0)
        float bxi = floorf(cx * 100.0f);
        float byi = floorf(cy * 100.0f);
        float bzi = floorf(cz * 100.0f);

        // base coord: strict f32 mul, protected from fusion
        float bx = bxi * VS; NOFUSE(bx);
        float by = byi * VS; NOFUSE(by);
        float bz = bzi * VS; NOFUSE(bz);

        int   hidx[8];
        float w[8];
#pragma unroll
        for (int k = 0; k < 8; ++k) {
            float vx = bx + ox[k]; NOFUSE(vx);   // strict add
            float vy = by + oy[k]; NOFUSE(vy);
            float vz = bz + oz[k]; NOFUSE(vz);

            float px = vx * P0; NOFUSE(px);              // round(vx*P0)
            float h  = __builtin_fmaf(vz, P2,
                       __builtin_fmaf(vy, P1, px));      // fused chain

            // exact mod 2^22 (h >= 0)
            float q  = truncf(h * 2.384185791015625e-07f);  // h * 2^-22
            float hm = h - q * 4194304.0f;                  // exact
            hidx[k] = (int)hm;

            float dx = cx - vx, dy = cy - vy, dz = cz - vz;
            w[k] = sqrtf(dx * dx + dy * dy + dz * dz) * inv_diag;
        }

        // issue all 8 row-slice loads first (max memory-level parallelism)
        f32x4 r[8];
#pragma unroll
        for (int k = 0; k < 8; ++k) {
            r[k] = ((const f32x4*)(table + (size_t)hidx[k] * 16))[col];
        }

        f32x4 acc = {0.f, 0.f, 0.f, 0.f};
#pragma unroll
        for (int k = 0; k < 8; ++k) {
            acc += r[k] * w[k];
        }

        // non-temporal store: no write-allocate, keep L3 for the table
        __builtin_nontemporal_store(acc, (f32x4*)(out + (size_t)p * 16) + col);
    }
}

extern "C" void kernel_launch(void* const* d_in, const int* in_sizes, int n_in,
                              void* d_out, int out_size, void* d_ws, size_t ws_size,
                              hipStream_t stream) {
    const float* coords = (const float*)d_in[0];   // (4096,128,3)
    const float* table  = (const float*)d_in[1];   // (2^22, 16)
    float* out = (float*)d_out;                    // (4096,128,16)

    int npts = in_sizes[0] / 3;                    // 524288
    int block = 256;
    int grid = 2048;                               // persistent: 8 blocks/CU
    hash_gather_kernel<<<grid, block, 0, stream>>>(coords, table, out, npts);
}